// Round 5
// baseline (106.770 us; speedup 1.0000x reference)
//
#include <hip/hip_runtime.h>
#include <math.h>

#define N_LEAVES 65536
#define WAVES 24
#define WC 2048
#define KSPLITS 3
#define S 128
#define N_INT (WAVES * WC)   // 49152 internal clades
#define G 2048
#define E_ITERS 50
#define EPS 1e-30f

#define NBLK 256
#define TPB 512   // 8 wavefronts/block; 256 blocks * 8 = 2048 wavefronts

#define AGENT __HIP_MEMORY_SCOPE_AGENT
#define SENT8 0xFFFFFFFFFFFFFFFFull
#define SENT4 0xFFFFFFFFu

union F2U { float2 f; unsigned long long u; };

// ---------------------------------------------------------------------------
// init: sentinel-fill P (25.2 MB) and meta (rsum,ls pairs, 0.4 MB); zero out.
// P values are probabilities in [0,1], rsum/ls finite -> all-ones bit
// patterns can never be produced by real data: the data IS the ready flag.
// ---------------------------------------------------------------------------
__global__ __launch_bounds__(256) void init_kernel(uint4* __restrict__ P4,
                                                   unsigned long long* __restrict__ meta,
                                                   float* __restrict__ out) {
    const int NP4 = N_INT * S / 4;   // 1,572,864 uint4
    int idx = blockIdx.x * 256 + threadIdx.x;
    int stride = gridDim.x * 256;
    uint4 s4 = make_uint4(SENT4, SENT4, SENT4, SENT4);
    for (int i = idx; i < NP4; i += stride) P4[i] = s4;
    for (int i = idx; i < N_INT; i += stride) meta[i] = SENT8;
    if (idx == 0) out[0] = 0.0f;
}

__device__ __forceinline__ unsigned long long frag_load(const float* __restrict__ P,
                                                        int r, int lane) {
    return __hip_atomic_load((const unsigned long long*)(P + (size_t)r * S) + lane,
                             __ATOMIC_RELAXED, AGENT);
}
__device__ __forceinline__ float rsum_load(const unsigned long long* __restrict__ meta,
                                           int r) {
    unsigned u = __hip_atomic_load((const unsigned*)(meta + r), __ATOMIC_RELAXED, AGENT);
    return __uint_as_float(u);
}

// ---- slot state (named variables; all indices compile-time -> registers) ----
#define SLOT_DECL(Sx)                                                          \
  float2 pv##Sx[6]; float rs##Sx[6]; int pidx##Sx[6]; float wq##Sx[3];         \
  int pend##Sx = 0, leafm##Sx = 0, wave##Sx = 0, valid##Sx = 0;

// refill slot with wave `nextWave` (in-order fill): load indices + logits,
// softmax, classify children, ISSUE gathers for internal-past children.
// Leaf species id is stashed in pidx (one-hot built at fire).
#define REFILL(Sx)                                                             \
  if (nextWave < WAVES) {                                                      \
    wave##Sx = nextWave; valid##Sx = 1;                                        \
    const int b_ = (nextWave * WC + c) * KSPLITS;                              \
    const int lo_ = N_LEAVES + nextWave * WC;                                  \
    float l0_ = logw[b_], l1_ = logw[b_ + 1], l2_ = logw[b_ + 2];              \
    float m_ = fmaxf(l0_, fmaxf(l1_, l2_));                                    \
    float e0_ = expf(l0_ - m_), e1_ = expf(l1_ - m_), e2_ = expf(l2_ - m_);    \
    float inv_ = 1.0f / (e0_ + e1_ + e2_);                                     \
    wq##Sx[0] = e0_ * inv_; wq##Sx[1] = e1_ * inv_; wq##Sx[2] = e2_ * inv_;    \
    pend##Sx = 0; leafm##Sx = 0;                                               \
    _Pragma("unroll")                                                          \
    for (int j_ = 0; j_ < 6; ++j_) {                                           \
      int idx_ = (j_ < 3) ? left[b_ + j_] : right[b_ + j_ - 3];                \
      float2 v_ = make_float2(0.f, 0.f);                                       \
      float rs_ = 0.f;                                                         \
      if (idx_ < N_LEAVES) {                                                   \
        leafm##Sx |= 1 << j_;                                                  \
        idx_ = leaf_species[idx_];                                             \
      } else if (idx_ < lo_) {                                                 \
        pend##Sx |= 1 << j_;                                                   \
        int r_ = idx_ - N_LEAVES;                                              \
        F2U u_; u_.u = frag_load(P, r_, lane);                                 \
        v_ = u_.f;                                                             \
        rs_ = rsum_load(meta, r_);                                             \
      }                                                                        \
      pidx##Sx[j_] = idx_; pv##Sx[j_] = v_; rs##Sx[j_] = rs_;                  \
    }                                                                          \
    ++nextWave;                                                                \
  } else valid##Sx = 0;

// one poll pass over a slot's pending children (no spin inside)
#define RESOLVE(Sx)                                                            \
  if (valid##Sx && pend##Sx) {                                                 \
    int done_ = 0;                                                             \
    _Pragma("unroll")                                                          \
    for (int j_ = 0; j_ < 6; ++j_)                                             \
      if ((pend##Sx >> j_) & 1) {                                              \
        int r_ = pidx##Sx[j_] - N_LEAVES;                                      \
        F2U u_; u_.f = pv##Sx[j_];                                             \
        if (u_.u == SENT8) { u_.u = frag_load(P, r_, lane); pv##Sx[j_] = u_.f; } \
        if (__float_as_uint(rs##Sx[j_]) == SENT4)                              \
          rs##Sx[j_] = rsum_load(meta, r_);                                    \
        if (__all((u_.u != SENT8) && (__float_as_uint(rs##Sx[j_]) != SENT4)))  \
          done_ |= 1 << j_;                                                    \
      }                                                                        \
    pend##Sx &= ~done_;                                                        \
  }

// compute + publish a ready slot, then count it
#define FIRE(Sx)                                                               \
  {                                                                            \
    _Pragma("unroll")                                                          \
    for (int j_ = 0; j_ < 6; ++j_)                                             \
      if ((leafm##Sx >> j_) & 1) {                                             \
        int sp_ = pidx##Sx[j_];                                                \
        pv##Sx[j_].x = (sp_ == 2 * lane) ? 1.f : 0.f;                          \
        pv##Sx[j_].y = (sp_ == 2 * lane + 1) ? 1.f : 0.f;                      \
        rs##Sx[j_] = 1.f;                                                      \
      }                                                                        \
    float v0_ = 0.f, v1_ = 0.f;                                                \
    _Pragma("unroll")                                                          \
    for (int jj_ = 0; jj_ < KSPLITS; ++jj_) {                                  \
      float2 a_ = pv##Sx[jj_], b_ = pv##Sx[jj_ + 3];                           \
      float sl_ = rs##Sx[jj_], sr_ = rs##Sx[jj_ + 3], w_ = wq##Sx[jj_];        \
      v0_ += w_ * (onepD * a_.x * b_.x +                                       \
                   T127 * (a_.x * (sr_ - b_.x) + b_.x * (sl_ - a_.x)));        \
      v1_ += w_ * (onepD * a_.y * b_.y +                                       \
                   T127 * (a_.y * (sr_ - b_.y) + b_.y * (sl_ - a_.y)));        \
    }                                                                          \
    v0_ /= denom; v1_ /= denom;                                                \
    float mx_ = fmaxf(v0_, v1_);                                               \
    float tt_ = v0_ + v1_;                                                     \
    _Pragma("unroll")                                                          \
    for (int d_ = 1; d_ < 64; d_ <<= 1) {                                      \
      mx_ = fmaxf(mx_, __shfl_xor(mx_, d_));                                   \
      tt_ += __shfl_xor(tt_, d_);                                              \
    }                                                                          \
    const float safe_ = fmaxf(mx_, EPS);                                       \
    const int row_ = wave##Sx * WC + c;                                        \
    F2U o_; o_.f = make_float2(v0_ / safe_, v1_ / safe_);                      \
    __hip_atomic_store((unsigned long long*)(P + (size_t)row_ * S) + lane,     \
                       o_.u, __ATOMIC_RELAXED, AGENT);                         \
    if (lane == 0) {                                                           \
      F2U mo_; mo_.f = make_float2(tt_ / safe_, logf(safe_));                  \
      __hip_atomic_store(&meta[row_], mo_.u, __ATOMIC_RELAXED, AGENT);         \
    }                                                                          \
    ++published;                                                               \
  }

// ---------------------------------------------------------------------------
// fused: out-of-order 3-slot window dataflow. Slots fill with waves in
// increasing order but FIRE in dependency-ready order — a stall on one
// wave no longer delays this wavefront's other independent clades.
// ---------------------------------------------------------------------------
__global__ __launch_bounds__(TPB, 2) void fused_kernel(
    const float* __restrict__ theta, const float* __restrict__ logw,
    const int* __restrict__ left, const int* __restrict__ right,
    const int* __restrict__ leaf_species, const int* __restrict__ root_ids,
    float* __restrict__ P, unsigned long long* __restrict__ meta,
    float* __restrict__ out) {
    const int lane = threadIdx.x & 63;
    const int c = blockIdx.x * (TPB / 64) + (threadIdx.x >> 6);  // clade slot

    // DTL rates + extinction fixed point (e uniform across species ->
    // mean(e) == e bitwise; scalar iteration).
    const float D = exp2f(theta[0]);
    const float L = exp2f(theta[1]);
    const float T = exp2f(theta[2]);
    const float norm = D + L + T + 1.0f;
    float e = L / norm;
#pragma unroll 1
    for (int i = 0; i < E_ITERS; ++i)
        e = (L + D * e * e + T * e * e) / norm;
    const float denom = 1.0f + D * e + T * e;
    const float onepD = 1.0f + D;
    const float T127 = T / 127.0f;

    int nextWave = 0, published = 0;
    SLOT_DECL(A) SLOT_DECL(B) SLOT_DECL(E)

    REFILL(A) REFILL(B) REFILL(E)

    while (published < WAVES) {
        RESOLVE(A) RESOLVE(B) RESOLVE(E)
        int fired = 0;
        if (validA && !pendA) { FIRE(A) REFILL(A) fired = 1; }
        if (validB && !pendB) { FIRE(B) REFILL(B) fired = 1; }
        if (validE && !pendE) { FIRE(E) REFILL(E) fired = 1; }
        if (!fired) __builtin_amdgcn_s_sleep(1);
    }

    // final: per-family ll from the root row's meta (rsum, ls) — one 8B poll
    // (single-copy-atomic publish => both words flip together). Leaf roots
    // contribute exactly 0 — skipped bitwise.
    const int r = root_ids[c];
    if (r >= N_LEAVES && lane == 0) {
        const int row = r - N_LEAVES;
        F2U m;
        while ((m.u = __hip_atomic_load(&meta[row], __ATOMIC_RELAXED, AGENT)) == SENT8)
            __builtin_amdgcn_s_sleep(1);
        atomicAdd(out, -(logf(m.f.x + EPS) + m.f.y));
    }
}

// ---------------------------------------------------------------------------
extern "C" void kernel_launch(void* const* d_in, const int* in_sizes, int n_in,
                              void* d_out, int out_size, void* d_ws, size_t ws_size,
                              hipStream_t stream) {
    const float* theta        = (const float*)d_in[0];
    const float* logw         = (const float*)d_in[1];
    const int*   left         = (const int*)d_in[2];
    const int*   right        = (const int*)d_in[3];
    const int*   leaf_species = (const int*)d_in[4];
    const int*   root_ids     = (const int*)d_in[5];
    float* out = (float*)d_out;

    char* ws = (char*)d_ws;
    float* P = (float*)ws;                                        // 25.17 MB
    unsigned long long* meta =
        (unsigned long long*)(ws + (size_t)N_INT * S * 4);        // 0.39 MB

    init_kernel<<<2048, 256, 0, stream>>>((uint4*)P, meta, out);
    fused_kernel<<<NBLK, TPB, 0, stream>>>(theta, logw, left, right,
                                           leaf_species, root_ids,
                                           P, meta, out);
}

// Round 6
// 99.704 us; speedup vs baseline: 1.0709x; 1.0709x over previous
//
#include <hip/hip_runtime.h>
#include <math.h>

#define N_LEAVES 65536
#define WAVES 24
#define WC 2048
#define KSPLITS 3
#define S 128
#define N_INT (WAVES * WC)   // 49152 internal clades
#define G 2048
#define E_ITERS 50
#define EPS 1e-30f

#define NBLK 256
#define TPB 512   // 8 wavefronts/block; 256 blocks * 8 = 2048 wavefronts

#define AGENT __HIP_MEMORY_SCOPE_AGENT
#define SENT8 0xFFFFFFFFFFFFFFFFull
#define SENT4 0xFFFFFFFFu

union F2U { float2 f; unsigned long long u; };

// ---------------------------------------------------------------------------
// init: sentinel-fill P (25.2 MB) and meta (rsum,ls pairs); zero out.
// P holds probabilities in [0,1], meta holds finite reals -> the all-ones
// (NaN) pattern can never be produced by real data: data IS the ready flag.
// ---------------------------------------------------------------------------
__global__ __launch_bounds__(256) void init_kernel(uint4* __restrict__ P4,
                                                   unsigned long long* __restrict__ meta,
                                                   float* __restrict__ out) {
    const int NP4 = N_INT * S / 4;   // 1,572,864 uint4
    int idx = blockIdx.x * 256 + threadIdx.x;
    int stride = gridDim.x * 256;
    uint4 s4 = make_uint4(SENT4, SENT4, SENT4, SENT4);
    for (int i = idx; i < NP4; i += stride) P4[i] = s4;
    for (int i = idx; i < N_INT; i += stride) meta[i] = SENT8;
    if (idx == 0) out[0] = 0.0f;
}

__device__ __forceinline__ unsigned long long frag_load(const float* __restrict__ P,
                                                        int r, int lane) {
    return __hip_atomic_load((const unsigned long long*)(P + (size_t)r * S) + lane,
                             __ATOMIC_RELAXED, AGENT);
}
__device__ __forceinline__ float rsum_load(const unsigned long long* __restrict__ meta,
                                           int r) {
    unsigned u = __hip_atomic_load((const unsigned*)(meta + r), __ATOMIC_RELAXED, AGENT);
    return __uint_as_float(u);
}

// ---- per-slot state (named vars, compile-time indices -> registers) --------
#define SLOT_DECL(Sx)                                                          \
  float2 pv##Sx[6]; float rs##Sx[6]; int pidx##Sx[6]; float wq##Sx[3];         \
  int pend##Sx = 0, leafm##Sx = 0;

// refill slot with wave KK (guarded): load indices + logits, softmax,
// classify children, ISSUE all gathers. Leaf species stashed in pidx.
#define REFILL(Sx, KK)                                                         \
  {                                                                            \
    const int kk_ = (KK);                                                      \
    if (kk_ < WAVES) {                                                         \
      const int b_ = (kk_ * WC + c) * KSPLITS;                                 \
      const int lo_ = N_LEAVES + kk_ * WC;                                     \
      float l0_ = logw[b_], l1_ = logw[b_ + 1], l2_ = logw[b_ + 2];            \
      float m_ = fmaxf(l0_, fmaxf(l1_, l2_));                                  \
      float e0_ = expf(l0_ - m_), e1_ = expf(l1_ - m_), e2_ = expf(l2_ - m_);  \
      float inv_ = 1.0f / (e0_ + e1_ + e2_);                                   \
      wq##Sx[0] = e0_ * inv_; wq##Sx[1] = e1_ * inv_; wq##Sx[2] = e2_ * inv_;  \
      pend##Sx = 0; leafm##Sx = 0;                                             \
      _Pragma("unroll")                                                        \
      for (int j_ = 0; j_ < 6; ++j_) {                                         \
        int idx_ = (j_ < 3) ? left[b_ + j_] : right[b_ + j_ - 3];              \
        float2 v_ = make_float2(0.f, 0.f);                                     \
        float rs_ = 0.f;                                                       \
        if (idx_ < N_LEAVES) {                                                 \
          leafm##Sx |= 1 << j_;                                                \
          idx_ = leaf_species[idx_];                                           \
        } else if (idx_ < lo_) {                                               \
          pend##Sx |= 1 << j_;                                                 \
          int r_ = idx_ - N_LEAVES;                                            \
          F2U u_; u_.u = frag_load(P, r_, lane);                               \
          v_ = u_.f;                                                           \
          rs_ = rsum_load(meta, r_);                                           \
        }                                                                      \
        pidx##Sx[j_] = idx_; pv##Sx[j_] = v_; rs##Sx[j_] = rs_;                \
      }                                                                        \
    }                                                                          \
  }

// spin until all of the slot's pending children are resolved
#define RESOLVE_SPIN(Sx)                                                       \
  while (pend##Sx) {                                                           \
    int done_ = 0;                                                             \
    _Pragma("unroll")                                                          \
    for (int j_ = 0; j_ < 6; ++j_)                                             \
      if ((pend##Sx >> j_) & 1) {                                              \
        int r_ = pidx##Sx[j_] - N_LEAVES;                                      \
        F2U u_; u_.f = pv##Sx[j_];                                             \
        if (u_.u == SENT8) { u_.u = frag_load(P, r_, lane); pv##Sx[j_] = u_.f; } \
        if (__float_as_uint(rs##Sx[j_]) == SENT4)                              \
          rs##Sx[j_] = rsum_load(meta, r_);                                    \
        if (__all((u_.u != SENT8) && (__float_as_uint(rs##Sx[j_]) != SENT4)))  \
          done_ |= 1 << j_;                                                    \
      }                                                                        \
    pend##Sx &= ~done_;                                                        \
    if (pend##Sx) __builtin_amdgcn_s_sleep(1);                                 \
  }

// compute + publish wave KK from a fully-resolved slot (bit-identical to r4)
#define FIRE(Sx, KK)                                                           \
  {                                                                            \
    _Pragma("unroll")                                                          \
    for (int j_ = 0; j_ < 6; ++j_)                                             \
      if ((leafm##Sx >> j_) & 1) {                                             \
        int sp_ = pidx##Sx[j_];                                                \
        pv##Sx[j_].x = (sp_ == 2 * lane) ? 1.f : 0.f;                          \
        pv##Sx[j_].y = (sp_ == 2 * lane + 1) ? 1.f : 0.f;                      \
        rs##Sx[j_] = 1.f;                                                      \
      }                                                                        \
    float v0_ = 0.f, v1_ = 0.f;                                                \
    _Pragma("unroll")                                                          \
    for (int jj_ = 0; jj_ < KSPLITS; ++jj_) {                                  \
      float2 a_ = pv##Sx[jj_], b_ = pv##Sx[jj_ + 3];                           \
      float sl_ = rs##Sx[jj_], sr_ = rs##Sx[jj_ + 3], w_ = wq##Sx[jj_];        \
      v0_ += w_ * (onepD * a_.x * b_.x +                                       \
                   T127 * (a_.x * (sr_ - b_.x) + b_.x * (sl_ - a_.x)));        \
      v1_ += w_ * (onepD * a_.y * b_.y +                                       \
                   T127 * (a_.y * (sr_ - b_.y) + b_.y * (sl_ - a_.y)));        \
    }                                                                          \
    v0_ /= denom; v1_ /= denom;                                                \
    float mx_ = fmaxf(v0_, v1_);                                               \
    float tt_ = v0_ + v1_;                                                     \
    _Pragma("unroll")                                                          \
    for (int d_ = 1; d_ < 64; d_ <<= 1) {                                      \
      mx_ = fmaxf(mx_, __shfl_xor(mx_, d_));                                   \
      tt_ += __shfl_xor(tt_, d_);                                              \
    }                                                                          \
    const float safe_ = fmaxf(mx_, EPS);                                       \
    const int row_ = (KK) * WC + c;                                            \
    F2U o_; o_.f = make_float2(v0_ / safe_, v1_ / safe_);                      \
    __hip_atomic_store((unsigned long long*)(P + (size_t)row_ * S) + lane,     \
                       o_.u, __ATOMIC_RELAXED, AGENT);                         \
    if (lane == 0) {                                                           \
      F2U mo_; mo_.f = make_float2(tt_ / safe_, logf(safe_));                  \
      __hip_atomic_store(&meta[row_], mo_.u, __ATOMIC_RELAXED, AGENT);         \
    }                                                                          \
  }

// ---------------------------------------------------------------------------
// fused: in-order firing with a 3-deep prefetch pipeline. Wave k's gathers
// (addresses static in left/right) are issued at wave k-3 — ~2 slot-phases
// of slack hide the IF latency for old children; only fresh (k-1/k-2)
// children may still poll at resolve.
// ---------------------------------------------------------------------------
__global__ __launch_bounds__(TPB, 2) void fused_kernel(
    const float* __restrict__ theta, const float* __restrict__ logw,
    const int* __restrict__ left, const int* __restrict__ right,
    const int* __restrict__ leaf_species, const int* __restrict__ root_ids,
    float* __restrict__ P, unsigned long long* __restrict__ meta,
    float* __restrict__ out) {
    const int lane = threadIdx.x & 63;
    const int c = blockIdx.x * (TPB / 64) + (threadIdx.x >> 6);  // clade slot

    // DTL rates + extinction fixed point (e uniform across species ->
    // mean(e) == e bitwise; scalar iteration).
    const float D = exp2f(theta[0]);
    const float L = exp2f(theta[1]);
    const float T = exp2f(theta[2]);
    const float norm = D + L + T + 1.0f;
    float e = L / norm;
#pragma unroll 1
    for (int i = 0; i < E_ITERS; ++i)
        e = (L + D * e * e + T * e * e) / norm;
    const float denom = 1.0f + D * e + T * e;
    const float onepD = 1.0f + D;
    const float T127 = T / 127.0f;

    SLOT_DECL(A) SLOT_DECL(B) SLOT_DECL(Cc)

    REFILL(A, 0) REFILL(B, 1) REFILL(Cc, 2)

#pragma unroll 1
    for (int k = 0; k < WAVES; k += 3) {
        RESOLVE_SPIN(A)  FIRE(A, k)      REFILL(A, k + 3)
        RESOLVE_SPIN(B)  FIRE(B, k + 1)  REFILL(B, k + 4)
        RESOLVE_SPIN(Cc) FIRE(Cc, k + 2) REFILL(Cc, k + 5)
    }

    // final: per-family ll from the root row's meta (rsum, ls) — one 8B poll
    // (single-copy-atomic publish => both words flip together). Leaf roots
    // contribute exactly 0 — skipped bitwise.
    const int r = root_ids[c];
    if (r >= N_LEAVES && lane == 0) {
        const int row = r - N_LEAVES;
        F2U m;
        while ((m.u = __hip_atomic_load(&meta[row], __ATOMIC_RELAXED, AGENT)) == SENT8)
            __builtin_amdgcn_s_sleep(1);
        atomicAdd(out, -(logf(m.f.x + EPS) + m.f.y));
    }
}

// ---------------------------------------------------------------------------
extern "C" void kernel_launch(void* const* d_in, const int* in_sizes, int n_in,
                              void* d_out, int out_size, void* d_ws, size_t ws_size,
                              hipStream_t stream) {
    const float* theta        = (const float*)d_in[0];
    const float* logw         = (const float*)d_in[1];
    const int*   left         = (const int*)d_in[2];
    const int*   right        = (const int*)d_in[3];
    const int*   leaf_species = (const int*)d_in[4];
    const int*   root_ids     = (const int*)d_in[5];
    float* out = (float*)d_out;

    char* ws = (char*)d_ws;
    float* P = (float*)ws;                                        // 25.17 MB
    unsigned long long* meta =
        (unsigned long long*)(ws + (size_t)N_INT * S * 4);        // 0.39 MB

    init_kernel<<<2048, 256, 0, stream>>>((uint4*)P, meta, out);
    fused_kernel<<<NBLK, TPB, 0, stream>>>(theta, logw, left, right,
                                           leaf_species, root_ids,
                                           P, meta, out);
}

// Round 7
// 74.453 us; speedup vs baseline: 1.4341x; 1.3392x over previous
//
#include <hip/hip_runtime.h>
#include <math.h>

#define N_LEAVES 65536
#define WAVES 24
#define WC 2048
#define KSPLITS 3
#define S 128
#define N_INT (WAVES * WC)   // 49152 internal clades
#define G 2048
#define E_ITERS 50
#define EPS 1e-30f

#define NBLK 512
#define TPB 512   // 8 wavefronts/block; 512*8 = 4096 wavefronts = 2 per clade slot

#define AGENT __HIP_MEMORY_SCOPE_AGENT
#define SENT8 0xFFFFFFFFFFFFFFFFull
#define SENT4 0xFFFFFFFFu

union F2U { float2 f; unsigned long long u; };

// ---------------------------------------------------------------------------
// init: sentinel-fill P (25.2 MB) and meta (rsum,ls pairs); zero out.
// P holds probabilities in [0,1], meta holds finite reals -> the all-ones
// (NaN) pattern can never be produced by real data: data IS the ready flag.
// ---------------------------------------------------------------------------
__global__ __launch_bounds__(256) void init_kernel(uint4* __restrict__ P4,
                                                   unsigned long long* __restrict__ meta,
                                                   float* __restrict__ out) {
    const int NP4 = N_INT * S / 4;   // 1,572,864 uint4
    int idx = blockIdx.x * 256 + threadIdx.x;
    int stride = gridDim.x * 256;
    uint4 s4 = make_uint4(SENT4, SENT4, SENT4, SENT4);
    for (int i = idx; i < NP4; i += stride) P4[i] = s4;
    for (int i = idx; i < N_INT; i += stride) meta[i] = SENT8;
    if (idx == 0) out[0] = 0.0f;
}

__device__ __forceinline__ unsigned long long frag_load(const float* __restrict__ P,
                                                        int r, int lane) {
    return __hip_atomic_load((const unsigned long long*)(P + (size_t)r * S) + lane,
                             __ATOMIC_RELAXED, AGENT);
}
__device__ __forceinline__ float rsum_load(const unsigned long long* __restrict__ meta,
                                           int r) {
    unsigned u = __hip_atomic_load((const unsigned*)(meta + r), __ATOMIC_RELAXED, AGENT);
    return __uint_as_float(u);
}

// ---- per-slot state (named vars, compile-time indices -> registers) --------
#define SLOT_DECL(Sx)                                                          \
  float2 pv##Sx[6]; float rs##Sx[6]; int pidx##Sx[6]; float wq##Sx[3];         \
  int pend##Sx = 0, leafm##Sx = 0;

// refill slot with wave KK (guarded): load indices + logits, softmax,
// classify children, ISSUE all gathers. Leaf species stashed in pidx.
#define REFILL(Sx, KK)                                                         \
  {                                                                            \
    const int kk_ = (KK);                                                      \
    if (kk_ < WAVES) {                                                         \
      const int b_ = (kk_ * WC + c) * KSPLITS;                                 \
      const int lo_ = N_LEAVES + kk_ * WC;                                     \
      float l0_ = logw[b_], l1_ = logw[b_ + 1], l2_ = logw[b_ + 2];            \
      float m_ = fmaxf(l0_, fmaxf(l1_, l2_));                                  \
      float e0_ = expf(l0_ - m_), e1_ = expf(l1_ - m_), e2_ = expf(l2_ - m_);  \
      float inv_ = 1.0f / (e0_ + e1_ + e2_);                                   \
      wq##Sx[0] = e0_ * inv_; wq##Sx[1] = e1_ * inv_; wq##Sx[2] = e2_ * inv_;  \
      pend##Sx = 0; leafm##Sx = 0;                                             \
      _Pragma("unroll")                                                        \
      for (int j_ = 0; j_ < 6; ++j_) {                                         \
        int idx_ = (j_ < 3) ? left[b_ + j_] : right[b_ + j_ - 3];              \
        float2 v_ = make_float2(0.f, 0.f);                                     \
        float rs_ = 0.f;                                                       \
        if (idx_ < N_LEAVES) {                                                 \
          leafm##Sx |= 1 << j_;                                                \
          idx_ = leaf_species[idx_];                                           \
        } else if (idx_ < lo_) {                                               \
          pend##Sx |= 1 << j_;                                                 \
          int r_ = idx_ - N_LEAVES;                                            \
          F2U u_; u_.u = frag_load(P, r_, lane);                               \
          v_ = u_.f;                                                           \
          rs_ = rsum_load(meta, r_);                                           \
        }                                                                      \
        pidx##Sx[j_] = idx_; pv##Sx[j_] = v_; rs##Sx[j_] = rs_;                \
      }                                                                        \
    }                                                                          \
  }

// spin until all of the slot's pending children are resolved
#define RESOLVE_SPIN(Sx)                                                       \
  while (pend##Sx) {                                                           \
    int done_ = 0;                                                             \
    _Pragma("unroll")                                                          \
    for (int j_ = 0; j_ < 6; ++j_)                                             \
      if ((pend##Sx >> j_) & 1) {                                              \
        int r_ = pidx##Sx[j_] - N_LEAVES;                                      \
        F2U u_; u_.f = pv##Sx[j_];                                             \
        if (u_.u == SENT8) { u_.u = frag_load(P, r_, lane); pv##Sx[j_] = u_.f; } \
        if (__float_as_uint(rs##Sx[j_]) == SENT4)                              \
          rs##Sx[j_] = rsum_load(meta, r_);                                    \
        if (__all((u_.u != SENT8) && (__float_as_uint(rs##Sx[j_]) != SENT4)))  \
          done_ |= 1 << j_;                                                    \
      }                                                                        \
    pend##Sx &= ~done_;                                                        \
    if (pend##Sx) __builtin_amdgcn_s_sleep(1);                                 \
  }

// compute + publish wave KK from a fully-resolved slot (bit-identical to r4)
#define FIRE(Sx, KK)                                                           \
  {                                                                            \
    _Pragma("unroll")                                                          \
    for (int j_ = 0; j_ < 6; ++j_)                                             \
      if ((leafm##Sx >> j_) & 1) {                                             \
        int sp_ = pidx##Sx[j_];                                                \
        pv##Sx[j_].x = (sp_ == 2 * lane) ? 1.f : 0.f;                          \
        pv##Sx[j_].y = (sp_ == 2 * lane + 1) ? 1.f : 0.f;                      \
        rs##Sx[j_] = 1.f;                                                      \
      }                                                                        \
    float v0_ = 0.f, v1_ = 0.f;                                                \
    _Pragma("unroll")                                                          \
    for (int jj_ = 0; jj_ < KSPLITS; ++jj_) {                                  \
      float2 a_ = pv##Sx[jj_], b_ = pv##Sx[jj_ + 3];                           \
      float sl_ = rs##Sx[jj_], sr_ = rs##Sx[jj_ + 3], w_ = wq##Sx[jj_];        \
      v0_ += w_ * (onepD * a_.x * b_.x +                                       \
                   T127 * (a_.x * (sr_ - b_.x) + b_.x * (sl_ - a_.x)));        \
      v1_ += w_ * (onepD * a_.y * b_.y +                                       \
                   T127 * (a_.y * (sr_ - b_.y) + b_.y * (sl_ - a_.y)));        \
    }                                                                          \
    v0_ /= denom; v1_ /= denom;                                                \
    float mx_ = fmaxf(v0_, v1_);                                               \
    float tt_ = v0_ + v1_;                                                     \
    _Pragma("unroll")                                                          \
    for (int d_ = 1; d_ < 64; d_ <<= 1) {                                      \
      mx_ = fmaxf(mx_, __shfl_xor(mx_, d_));                                   \
      tt_ += __shfl_xor(tt_, d_);                                              \
    }                                                                          \
    const float safe_ = fmaxf(mx_, EPS);                                       \
    const int row_ = (KK) * WC + c;                                            \
    F2U o_; o_.f = make_float2(v0_ / safe_, v1_ / safe_);                      \
    __hip_atomic_store((unsigned long long*)(P + (size_t)row_ * S) + lane,     \
                       o_.u, __ATOMIC_RELAXED, AGENT);                         \
    if (lane == 0) {                                                           \
      F2U mo_; mo_.f = make_float2(tt_ / safe_, logf(safe_));                  \
      __hip_atomic_store(&meta[row_], mo_.u, __ATOMIC_RELAXED, AGENT);         \
    }                                                                          \
  }

// ---------------------------------------------------------------------------
// fused: 4096 wavefronts (2 per clade slot, parity-split waves). Waves of
// one slot are independent clades -> splitting them across wavefronts costs
// no communication, doubles resident waves/SIMD (TLP latency hiding), and
// halves each wavefront's serial chain. Two-slot ping-pong, in-order fire.
// ---------------------------------------------------------------------------
__global__ __launch_bounds__(TPB, 4) void fused_kernel(
    const float* __restrict__ theta, const float* __restrict__ logw,
    const int* __restrict__ left, const int* __restrict__ right,
    const int* __restrict__ leaf_species, const int* __restrict__ root_ids,
    float* __restrict__ P, unsigned long long* __restrict__ meta,
    float* __restrict__ out) {
    const int lane = threadIdx.x & 63;
    const int w = blockIdx.x * (TPB / 64) + (threadIdx.x >> 6);  // 0..4095
    const int c = w >> 1;        // clade slot 0..2047
    const int q = w & 1;         // wave parity

    // DTL rates + extinction fixed point (e uniform across species ->
    // mean(e) == e bitwise; scalar iteration).
    const float D = exp2f(theta[0]);
    const float L = exp2f(theta[1]);
    const float T = exp2f(theta[2]);
    const float norm = D + L + T + 1.0f;
    float e = L / norm;
#pragma unroll 1
    for (int i = 0; i < E_ITERS; ++i)
        e = (L + D * e * e + T * e * e) / norm;
    const float denom = 1.0f + D * e + T * e;
    const float onepD = 1.0f + D;
    const float T127 = T / 127.0f;

    SLOT_DECL(A) SLOT_DECL(B)

    REFILL(A, q) REFILL(B, q + 2)

#pragma unroll 1
    for (int k = q; k < WAVES; k += 4) {
        RESOLVE_SPIN(A) FIRE(A, k)     REFILL(A, k + 4)
        RESOLVE_SPIN(B) FIRE(B, k + 2) REFILL(B, k + 6)
    }

    // final: per-family ll from the root row's meta (rsum, ls) — one 8B poll
    // (single-copy-atomic publish => both words flip together). Leaf roots
    // contribute exactly 0 — skipped bitwise. Parity-0 wavefront of slot c
    // handles family c.
    const int r = root_ids[c];
    if (q == 0 && r >= N_LEAVES && lane == 0) {
        const int row = r - N_LEAVES;
        F2U m;
        while ((m.u = __hip_atomic_load(&meta[row], __ATOMIC_RELAXED, AGENT)) == SENT8)
            __builtin_amdgcn_s_sleep(1);
        atomicAdd(out, -(logf(m.f.x + EPS) + m.f.y));
    }
}

// ---------------------------------------------------------------------------
extern "C" void kernel_launch(void* const* d_in, const int* in_sizes, int n_in,
                              void* d_out, int out_size, void* d_ws, size_t ws_size,
                              hipStream_t stream) {
    const float* theta        = (const float*)d_in[0];
    const float* logw         = (const float*)d_in[1];
    const int*   left         = (const int*)d_in[2];
    const int*   right        = (const int*)d_in[3];
    const int*   leaf_species = (const int*)d_in[4];
    const int*   root_ids     = (const int*)d_in[5];
    float* out = (float*)d_out;

    char* ws = (char*)d_ws;
    float* P = (float*)ws;                                        // 25.17 MB
    unsigned long long* meta =
        (unsigned long long*)(ws + (size_t)N_INT * S * 4);        // 0.39 MB

    init_kernel<<<2048, 256, 0, stream>>>((uint4*)P, meta, out);
    fused_kernel<<<NBLK, TPB, 0, stream>>>(theta, logw, left, right,
                                           leaf_species, root_ids,
                                           P, meta, out);
}